// Round 1
// baseline (1091.897 us; speedup 1.0000x reference)
//
#include <hip/hip_runtime.h>
#include <hip/hip_bf16.h>

#define NB 16
#define NC 256
#define NS 4096
#define NL 256
#define NE 256
#define NHH 4
#define HDD 64

using bf16 = __hip_bfloat16;

__device__ __forceinline__ float bf16r(float x) {
    return __bfloat162float(__float2bfloat16(x));
}
__device__ __forceinline__ float rsqrt_nr(float x) {
    float r = rsqrtf(x);
    r = r * (1.5f - 0.5f * x * r * r);  // one Newton step for LN precision
    return r;
}
__device__ __forceinline__ float wave_sum(float v) {
#pragma unroll
    for (int o = 32; o > 0; o >>= 1) v += __shfl_down(v, o, 64);
    return v;
}

// ---------------- K1: AdaLN modulation: mod = silu(ref_embeds) @ W_ada + b_ada
__global__ void __launch_bounds__(256) mod_kernel(const float* __restrict__ ref_embeds,
                                                  const float* __restrict__ W_ada,
                                                  const float* __restrict__ b_ada,
                                                  float* __restrict__ mod) {
    int b = blockIdx.x, t = threadIdx.x;
    __shared__ float silu[NC];
    float x = ref_embeds[b * NC + t];
    silu[t] = x / (1.f + expf(-x));
    __syncthreads();
    for (int rep = 0; rep < 3; rep++) {
        int j = rep * NC + t;
        float acc = b_ada[j];
        for (int c = 0; c < NC; c++) acc += silu[c] * W_ada[c * 3 * NC + j];
        mod[b * 3 * NC + j] = acc;
    }
}

// ---------------- K2: LN(refs) -> K,V projections (bf16 [B,L,E])
__global__ void __launch_bounds__(256) kv_kernel(const float* __restrict__ refs,
                                                 const float* __restrict__ lw,
                                                 const float* __restrict__ lb,
                                                 const float* __restrict__ Wk,
                                                 const float* __restrict__ bk,
                                                 const float* __restrict__ Wv,
                                                 const float* __restrict__ bv,
                                                 bf16* __restrict__ kbuf,
                                                 bf16* __restrict__ vbuf) {
    int row = blockIdx.x;  // b*NL + l
    int t = threadIdx.x;
    __shared__ float red[4];
    __shared__ float nrm[NC];
    const float* rp = refs + (size_t)row * NC;
    float r = rp[t];
    float s = wave_sum(r);
    if ((t & 63) == 0) red[t >> 6] = s;
    __syncthreads();
    float mu = (red[0] + red[1] + red[2] + red[3]) * (1.f / NC);
    __syncthreads();
    float d = r - mu;
    s = wave_sum(d * d);
    if ((t & 63) == 0) red[t >> 6] = s;
    __syncthreads();
    float var = (red[0] + red[1] + red[2] + red[3]) * (1.f / NC);
    float rs = rsqrt_nr(var + 1e-5f);
    nrm[t] = d * rs * lw[t] + lb[t];
    __syncthreads();
    float ka = bk[t], va = bv[t];
    for (int c = 0; c < NC; c++) {
        float n = nrm[c];
        ka += n * Wk[c * NE + t];
        va += n * Wv[c * NE + t];
    }
    kbuf[(size_t)row * NE + t] = __float2bfloat16(ka);
    vbuf[(size_t)row * NE + t] = __float2bfloat16(va);
}

// ---------------- K3: LN(img tokens) -> Q projection (bf16 [B,S,E])
// img_x is [B,C,S]; token s needs all C (stride S). Stage a [C x 32s] LDS tile
// with coalesced loads along s, LN per s-column, then project.
__global__ void __launch_bounds__(256) q_kernel(const float* __restrict__ img_x,
                                                const float* __restrict__ lw,
                                                const float* __restrict__ lb,
                                                const float* __restrict__ Wq,
                                                const float* __restrict__ bq,
                                                bf16* __restrict__ qbuf) {
    int blk = blockIdx.x;
    int b = blk >> 7;            // NS/32 = 128 tiles per batch
    int s0 = (blk & 127) << 5;
    int t = threadIdx.x;
    int sl = t & 31, ch = t >> 5;  // ch: 0..7
    __shared__ float tile[NC * 32];   // [c][s], stride 32 (2-way bank alias = free)
    __shared__ float part[256];
    __shared__ float mu_s[32], rs_s[32];
    const float* xp = img_x + ((size_t)b * NC) * NS + s0;
    for (int c0 = 0; c0 < 32; c0++) {
        int c = c0 * 8 + ch;
        tile[c * 32 + sl] = xp[(size_t)c * NS + sl];
    }
    __syncthreads();
    float ps = 0;
    for (int c = ch * 32; c < ch * 32 + 32; c++) ps += tile[c * 32 + sl];
    part[t] = ps;
    __syncthreads();
    if (t < 32) {
        float m = 0;
        for (int j = 0; j < 8; j++) m += part[j * 32 + t];
        mu_s[t] = m * (1.f / NC);
    }
    __syncthreads();
    float mu = mu_s[sl];
    ps = 0;
    for (int c = ch * 32; c < ch * 32 + 32; c++) {
        float d = tile[c * 32 + sl] - mu;
        ps += d * d;
    }
    part[t] = ps;
    __syncthreads();
    if (t < 32) {
        float vv = 0;
        for (int j = 0; j < 8; j++) vv += part[j * 32 + t];
        rs_s[t] = rsqrt_nr(vv * (1.f / NC) + 1e-5f);
    }
    __syncthreads();
    float rs = rs_s[sl];
    for (int c0 = 0; c0 < 32; c0++) {
        int c = c0 * 8 + ch;
        tile[c * 32 + sl] = (tile[c * 32 + sl] - mu) * rs * lw[c] + lb[c];
    }
    __syncthreads();
    // projection: thread = output channel e; 2 chunks x 16 s accumulators
    float bqv = bq[t];
    for (int half = 0; half < 2; half++) {
        float acc[16];
#pragma unroll
        for (int i = 0; i < 16; i++) acc[i] = 0;
        int sb = half * 16;
        for (int c = 0; c < NC; c++) {
            float w = Wq[c * NE + t];
            const float* tp = &tile[c * 32 + sb];  // broadcast reads
#pragma unroll
            for (int i = 0; i < 16; i++) acc[i] += tp[i] * w;
        }
#pragma unroll
        for (int i = 0; i < 16; i++) {
            int s = s0 + sb + i;
            qbuf[((size_t)b * NS + s) * NE + t] = __float2bfloat16(acc[i] + bqv);
        }
    }
}

// ---------------- K4: attention per (b, h, 64-query tile); L=256 keys fit fully.
// LDS budget exactly 64KB: bufA (32KB) = Q tile fp32 [64][65] -> softmax partials -> P^T bf16 [256][64]
//                          bufB (32KB) = K bf16 [256][64] -> reloaded with V after scores.
__global__ void __launch_bounds__(256) attn_kernel(const bf16* __restrict__ qbuf,
                                                   const bf16* __restrict__ kbuf,
                                                   const bf16* __restrict__ vbuf,
                                                   const int* __restrict__ masks,
                                                   bf16* __restrict__ obuf) {
    int blk = blockIdx.x;
    int st = blk & 63;
    int bh = blk >> 6;
    int h = bh & 3;
    int b = bh >> 2;
    int s0 = st << 6;
    int t = threadIdx.x;
    __shared__ char smA[32768];
    __shared__ char smB[32768];
    float* qt = (float*)smA;   // [64][65] fp32 (16.6 KB)
    float* red = (float*)smA;  // aliases qt AFTER dot phase (qt dead)
    bf16* pt = (bf16*)smA;     // [256 k][64 ql], written after softmax
    bf16* kv = (bf16*)smB;     // [256][64] bf16: K then V

    {   // loads: coalesced along d
        int d = t & 63, qr = t >> 6;
        const bf16* qp = qbuf + ((size_t)b * NS + s0) * NE + h * HDD;
        for (int r0 = 0; r0 < 16; r0++) {
            int q = r0 * 4 + qr;
            qt[q * 65 + d] = __bfloat162float(qp[(size_t)q * NE + d]);
        }
        const bf16* kp = kbuf + ((size_t)b * NL) * NE + h * HDD;
        for (int r0 = 0; r0 < 64; r0++) {
            int l = r0 * 4 + qr;
            kv[l * 64 + d] = kp[(size_t)l * NE + d];
        }
    }
    __syncthreads();

    int ql = t & 63, kc = t >> 6;  // within a wave kc is constant -> kv reads broadcast
    const int* mp = masks + b * NL;
    float sc_[64];
#pragma unroll
    for (int j = 0; j < 64; j++) sc_[j] = 0;
    for (int d0 = 0; d0 < 64; d0 += 16) {
        float qr_[16];
#pragma unroll
        for (int i = 0; i < 16; i++) qr_[i] = qt[ql * 65 + d0 + i];
#pragma unroll
        for (int j = 0; j < 64; j++) {
            const bf16* kp = &kv[(kc * 64 + j) * 64 + d0];
            float a = 0;
#pragma unroll
            for (int i = 0; i < 16; i++) a += qr_[i] * __bfloat162float(kp[i]);
            sc_[j] += a;
        }
    }
    __syncthreads();  // qt reads done; red/pt may now overwrite bufA

    // reference: scores = bf16(q@k^T) -> fp32 * scale -> mask -inf
#pragma unroll
    for (int j = 0; j < 64; j++) {
        int k = kc * 64 + j;
        float sv = bf16r(sc_[j]) * 0.125f;
        if (mp[k]) sv = -INFINITY;
        sc_[j] = sv;
    }
    // softmax over 256 keys: 4 partial owners per query row
    float mloc = -INFINITY;
#pragma unroll
    for (int j = 0; j < 64; j++) mloc = fmaxf(mloc, sc_[j]);
    red[kc * 64 + ql] = mloc;
    __syncthreads();
    float m = fmaxf(fmaxf(red[ql], red[64 + ql]), fmaxf(red[128 + ql], red[192 + ql]));
    __syncthreads();
    float sl_ = 0;
#pragma unroll
    for (int j = 0; j < 64; j++) {
        float p = __expf(sc_[j] - m);
        sc_[j] = p;
        sl_ += p;
    }
    red[kc * 64 + ql] = sl_;
    __syncthreads();
    float sum = red[ql] + red[64 + ql] + red[128 + ql] + red[192 + ql];
    __syncthreads();  // all red reads done before pt overwrites bufA
    float inv = 1.f / sum;
#pragma unroll
    for (int j = 0; j < 64; j++) {
        pt[(kc * 64 + j) * 64 + ql] = __float2bfloat16(sc_[j] * inv);
    }
    {   // reload bufB with V (K reads finished at the post-dot barrier)
        int d = t & 63, qr = t >> 6;
        const bf16* vp = vbuf + ((size_t)b * NL) * NE + h * HDD;
        for (int r0 = 0; r0 < 64; r0++) {
            int l = r0 * 4 + qr;
            kv[l * 64 + d] = vp[(size_t)l * NE + d];
        }
    }
    __syncthreads();

    // phase 2: O = P @ V ; thread = (query row, 16-wide d chunk)
    int ql2 = t >> 2, dc = t & 3;
    float oacc[16];
#pragma unroll
    for (int i = 0; i < 16; i++) oacc[i] = 0;
    for (int k = 0; k < NL; k++) {
        float p = __bfloat162float(pt[k * 64 + ql2]);
        const bf16* vp = &kv[k * 64 + dc * 16];
#pragma unroll
        for (int i = 0; i < 16; i++) oacc[i] += p * __bfloat162float(vp[i]);
    }
    bf16* op = obuf + ((size_t)b * NS + s0 + ql2) * NE + h * HDD + dc * 16;
#pragma unroll
    for (int i = 0; i < 16; i++) op[i] = __float2bfloat16(oacc[i]);
}

// ---------------- K5: attn@Wo + bo, AdaLN modulate, +residual, write NCHW
__global__ void __launch_bounds__(256) out_kernel(const bf16* __restrict__ obuf,
                                                  const float* __restrict__ Wo,
                                                  const float* __restrict__ bo,
                                                  const float* __restrict__ mod,
                                                  const float* __restrict__ img_x,
                                                  float* __restrict__ out) {
    int blk = blockIdx.x;
    int b = blk >> 7;
    int s0 = (blk & 127) << 5;
    int t = threadIdx.x;
    __shared__ float ot[NE * 33];   // o^T [e][s], pad 33 kills bank conflicts
    __shared__ float yt[NC * 17];   // y chunk [c][16s], pad 17
    const bf16* op = obuf + ((size_t)b * NS + s0) * NE;
    for (int r = 0; r < 32; r++) {
        ot[t * 33 + r] = __bfloat162float(op[(size_t)r * NE + t]);
    }
    __syncthreads();
    float sh = mod[b * 768 + t];
    float scv = mod[b * 768 + 256 + t];
    float ga = mod[b * 768 + 512 + t];
    float bov = bo[t];
    const float* xg = img_x + ((size_t)b * NC) * NS + s0;
    for (int half = 0; half < 2; half++) {
        float acc[16];
#pragma unroll
        for (int i = 0; i < 16; i++) acc[i] = 0;
        int sb = half * 16;
        for (int e = 0; e < NE; e++) {
            float w = Wo[e * NC + t];
            const float* pp = &ot[e * 33 + sb];  // broadcast
#pragma unroll
            for (int i = 0; i < 16; i++) acc[i] += pp[i] * w;
        }
#pragma unroll
        for (int i = 0; i < 16; i++) {
            float y = ga * ((acc[i] + bov) * (1.f + scv) + sh);
            yt[t * 17 + i] = y;
        }
        __syncthreads();
        int si = t & 15, cg = t >> 4;
        for (int it = 0; it < 16; it++) {
            int c = it * 16 + cg;
            int s = sb + si;
            out[((size_t)b * NC + c) * NS + s0 + s] = yt[c * 17 + si] + xg[(size_t)c * NS + s];
        }
        __syncthreads();  // yt reused next half
    }
}

extern "C" void kernel_launch(void* const* d_in, const int* in_sizes, int n_in,
                              void* d_out, int out_size, void* d_ws, size_t ws_size,
                              hipStream_t stream) {
    const float* img_x = (const float*)d_in[0];
    const float* refs = (const float*)d_in[1];
    const int* masks = (const int*)d_in[2];
    const float* ref_embeds = (const float*)d_in[3];
    const float* ln_img_w = (const float*)d_in[4];
    const float* ln_img_b = (const float*)d_in[5];
    const float* ln_txt_w = (const float*)d_in[6];
    const float* ln_txt_b = (const float*)d_in[7];
    const float* Wq = (const float*)d_in[8];
    const float* bq = (const float*)d_in[9];
    const float* Wk = (const float*)d_in[10];
    const float* bk = (const float*)d_in[11];
    const float* Wv = (const float*)d_in[12];
    const float* bv = (const float*)d_in[13];
    const float* Wo = (const float*)d_in[14];
    const float* bo = (const float*)d_in[15];
    const float* W_ada = (const float*)d_in[16];
    const float* b_ada = (const float*)d_in[17];
    float* out = (float*)d_out;

    char* ws = (char*)d_ws;
    float* mod = (float*)ws;                                      // 49,152 B
    bf16* kbuf = (bf16*)(ws + 49152);                             // 2 MB
    bf16* vbuf = (bf16*)(ws + 49152 + 2097152);                   // 2 MB
    bf16* qbuf = (bf16*)(ws + 49152 + 2 * 2097152);               // 33.5 MB
    bf16* obuf = (bf16*)(ws + 49152 + 2 * 2097152 + 33554432);    // 33.5 MB

    hipLaunchKernelGGL(mod_kernel, dim3(NB), dim3(256), 0, stream,
                       ref_embeds, W_ada, b_ada, mod);
    hipLaunchKernelGGL(kv_kernel, dim3(NB * NL), dim3(256), 0, stream,
                       refs, ln_txt_w, ln_txt_b, Wk, bk, Wv, bv, kbuf, vbuf);
    hipLaunchKernelGGL(q_kernel, dim3(NB * (NS / 32)), dim3(256), 0, stream,
                       img_x, ln_img_w, ln_img_b, Wq, bq, qbuf);
    hipLaunchKernelGGL(attn_kernel, dim3(NB * NHH * (NS / 64)), dim3(256), 0, stream,
                       qbuf, kbuf, vbuf, masks, obuf);
    hipLaunchKernelGGL(out_kernel, dim3(NB * (NS / 32)), dim3(256), 0, stream,
                       obuf, Wo, bo, mod, img_x, out);
}

// Round 2
// 744.177 us; speedup vs baseline: 1.4673x; 1.4673x over previous
//
#include <hip/hip_runtime.h>
#include <hip/hip_bf16.h>

#define NB 16
#define NC 256
#define NS 4096
#define NL 256
#define NE 256
#define NHH 4
#define HDD 64

using bf16 = __hip_bfloat16;
typedef short bf16x8 __attribute__((ext_vector_type(8)));
typedef float f32x4 __attribute__((ext_vector_type(4)));

__device__ __forceinline__ float bf16r(float x) {
    return __bfloat162float(__float2bfloat16(x));
}
__device__ __forceinline__ float rsqrt_nr(float x) {
    float r = rsqrtf(x);
    r = r * (1.5f - 0.5f * x * r * r);  // one Newton step for LN precision
    return r;
}
__device__ __forceinline__ float wave_sum(float v) {
#pragma unroll
    for (int o = 32; o > 0; o >>= 1) v += __shfl_down(v, o, 64);
    return v;
}

// ---------------- K1: AdaLN modulation: mod = silu(ref_embeds) @ W_ada + b_ada
__global__ void __launch_bounds__(256) mod_kernel(const float* __restrict__ ref_embeds,
                                                  const float* __restrict__ W_ada,
                                                  const float* __restrict__ b_ada,
                                                  float* __restrict__ mod) {
    int b = blockIdx.x, t = threadIdx.x;
    __shared__ float silu[NC];
    float x = ref_embeds[b * NC + t];
    silu[t] = x / (1.f + expf(-x));
    __syncthreads();
    for (int rep = 0; rep < 3; rep++) {
        int j = rep * NC + t;
        float acc = b_ada[j];
        for (int c = 0; c < NC; c++) acc += silu[c] * W_ada[c * 3 * NC + j];
        mod[b * 3 * NC + j] = acc;
    }
}

// ---------------- K2: LN(refs) -> K,V projections (bf16 [B,L,E])
__global__ void __launch_bounds__(256) kv_kernel(const float* __restrict__ refs,
                                                 const float* __restrict__ lw,
                                                 const float* __restrict__ lb,
                                                 const float* __restrict__ Wk,
                                                 const float* __restrict__ bk,
                                                 const float* __restrict__ Wv,
                                                 const float* __restrict__ bv,
                                                 bf16* __restrict__ kbuf,
                                                 bf16* __restrict__ vbuf) {
    int row = blockIdx.x;  // b*NL + l
    int t = threadIdx.x;
    __shared__ float red[4];
    __shared__ float nrm[NC];
    const float* rp = refs + (size_t)row * NC;
    float r = rp[t];
    float s = wave_sum(r);
    if ((t & 63) == 0) red[t >> 6] = s;
    __syncthreads();
    float mu = (red[0] + red[1] + red[2] + red[3]) * (1.f / NC);
    __syncthreads();
    float d = r - mu;
    s = wave_sum(d * d);
    if ((t & 63) == 0) red[t >> 6] = s;
    __syncthreads();
    float var = (red[0] + red[1] + red[2] + red[3]) * (1.f / NC);
    float rs = rsqrt_nr(var + 1e-5f);
    nrm[t] = d * rs * lw[t] + lb[t];
    __syncthreads();
    float ka = bk[t], va = bv[t];
    for (int c = 0; c < NC; c++) {
        float n = nrm[c];
        ka += n * Wk[c * NE + t];
        va += n * Wv[c * NE + t];
    }
    kbuf[(size_t)row * NE + t] = __float2bfloat16(ka);
    vbuf[(size_t)row * NE + t] = __float2bfloat16(va);
}

// ---------------- K2b: transpose V per head: vbuf [B,L,E] -> vtbuf [B,H,HD,L]
__global__ void __launch_bounds__(256) vt_kernel(const bf16* __restrict__ vbuf,
                                                 ushort* __restrict__ vtbuf) {
    int bh = blockIdx.x;  // b*NHH + h
    int b = bh >> 2, h = bh & 3;
    int t = threadIdx.x;
    __shared__ ushort tile[64 * 264];  // [d][l], stride 264 (16B-aligned rows, odd word stride/4)
    const ushort* vp = (const ushort*)vbuf + ((size_t)b * NL) * NE + h * HDD;
#pragma unroll
    for (int i = 0; i < 8; i++) {
        int l = i * 32 + (t >> 3);
        uint4 v = *(const uint4*)(vp + (size_t)l * NE + (t & 7) * 8);
        const ushort* v8 = (const ushort*)&v;
#pragma unroll
        for (int j = 0; j < 8; j++) tile[((t & 7) * 8 + j) * 264 + l] = v8[j];
    }
    __syncthreads();
    ushort* op = vtbuf + (size_t)bh * HDD * NL;
#pragma unroll
    for (int i = 0; i < 8; i++) {
        int d = i * 8 + (t >> 5);
        int l = (t & 31) * 8;
        *(uint4*)(op + (size_t)d * NL + l) = *(const uint4*)(tile + d * 264 + l);
    }
}

// ---------------- K3: LN(img tokens) -> Q projection (bf16 [B,S,E])
__global__ void __launch_bounds__(256) q_kernel(const float* __restrict__ img_x,
                                                const float* __restrict__ lw,
                                                const float* __restrict__ lb,
                                                const float* __restrict__ Wq,
                                                const float* __restrict__ bq,
                                                bf16* __restrict__ qbuf) {
    int blk = blockIdx.x;
    int b = blk >> 7;            // NS/32 = 128 tiles per batch
    int s0 = (blk & 127) << 5;
    int t = threadIdx.x;
    int sl = t & 31, ch = t >> 5;  // ch: 0..7
    __shared__ float tile[NC * 32];
    __shared__ float part[256];
    __shared__ float mu_s[32], rs_s[32];
    const float* xp = img_x + ((size_t)b * NC) * NS + s0;
    for (int c0 = 0; c0 < 32; c0++) {
        int c = c0 * 8 + ch;
        tile[c * 32 + sl] = xp[(size_t)c * NS + sl];
    }
    __syncthreads();
    float ps = 0;
    for (int c = ch * 32; c < ch * 32 + 32; c++) ps += tile[c * 32 + sl];
    part[t] = ps;
    __syncthreads();
    if (t < 32) {
        float m = 0;
        for (int j = 0; j < 8; j++) m += part[j * 32 + t];
        mu_s[t] = m * (1.f / NC);
    }
    __syncthreads();
    float mu = mu_s[sl];
    ps = 0;
    for (int c = ch * 32; c < ch * 32 + 32; c++) {
        float d = tile[c * 32 + sl] - mu;
        ps += d * d;
    }
    part[t] = ps;
    __syncthreads();
    if (t < 32) {
        float vv = 0;
        for (int j = 0; j < 8; j++) vv += part[j * 32 + t];
        rs_s[t] = rsqrt_nr(vv * (1.f / NC) + 1e-5f);
    }
    __syncthreads();
    float rs = rs_s[sl];
    for (int c0 = 0; c0 < 32; c0++) {
        int c = c0 * 8 + ch;
        tile[c * 32 + sl] = (tile[c * 32 + sl] - mu) * rs * lw[c] + lb[c];
    }
    __syncthreads();
    float bqv = bq[t];
    for (int half = 0; half < 2; half++) {
        float acc[16];
#pragma unroll
        for (int i = 0; i < 16; i++) acc[i] = 0;
        int sb = half * 16;
        for (int c = 0; c < NC; c++) {
            float w = Wq[c * NE + t];
            const float* tp = &tile[c * 32 + sb];
#pragma unroll
            for (int i = 0; i < 16; i++) acc[i] += tp[i] * w;
        }
#pragma unroll
        for (int i = 0; i < 16; i++) {
            int s = s0 + sb + i;
            qbuf[((size_t)b * NS + s) * NE + t] = __float2bfloat16(acc[i] + bqv);
        }
    }
}

// ---------------- K4: MFMA attention. Block = 4 waves, 64 queries, all 256 keys.
// Wave w owns queries s0+w*16 .. +15. QK^T B-frags direct from global kbuf,
// PV B-frags direct from global vtbuf (pre-transposed); only P round-trips LDS.
__global__ void __launch_bounds__(256) attn_kernel(const bf16* __restrict__ qbuf,
                                                   const bf16* __restrict__ kbuf,
                                                   const ushort* __restrict__ vtbuf,
                                                   const int* __restrict__ masks,
                                                   bf16* __restrict__ obuf) {
    int blk = blockIdx.x;
    int st = blk & 63;
    int bh = blk >> 6;
    int h = bh & 3;
    int b = bh >> 2;
    int s0 = st << 6;
    int t = threadIdx.x;
    int w = t >> 6, lane = t & 63;
    int l16 = lane & 15, quad = lane >> 4;

    __shared__ ushort sP[64 * 264];  // wave w owns rows w*16..w*16+15; stride 264

    // Q A-frags: A[m=lane&15][k=quad*8+j], k chunks 0..31 and 32..63
    const ushort* qp = (const ushort*)qbuf +
                       ((size_t)(b * NS + s0 + w * 16 + l16)) * NE + h * HDD + quad * 8;
    bf16x8 af0 = *(const bf16x8*)qp;
    bf16x8 af1 = *(const bf16x8*)(qp + 32);

    f32x4 zero = {0.f, 0.f, 0.f, 0.f};
    f32x4 acc[16];
#pragma unroll
    for (int kt = 0; kt < 16; kt++) acc[kt] = zero;

    const ushort* kp0 = (const ushort*)kbuf + ((size_t)(b * NL)) * NE + h * HDD + quad * 8;
#pragma unroll
    for (int kt = 0; kt < 16; kt++) {
        const ushort* kp = kp0 + (size_t)(kt * 16 + l16) * NE;
        bf16x8 bf0 = *(const bf16x8*)kp;
        bf16x8 bf1 = *(const bf16x8*)(kp + 32);
        acc[kt] = __builtin_amdgcn_mfma_f32_16x16x32_bf16(af0, bf0, acc[kt], 0, 0, 0);
        acc[kt] = __builtin_amdgcn_mfma_f32_16x16x32_bf16(af1, bf1, acc[kt], 0, 0, 0);
    }

    // scores: bf16 round, scale, mask; softmax across 256 keys.
    // C layout: lane holds rows quad*4+r, col l16 (+16*kt).
    const int* mp = masks + b * NL;
    float mrow[4] = {-INFINITY, -INFINITY, -INFINITY, -INFINITY};
#pragma unroll
    for (int kt = 0; kt < 16; kt++) {
        int mv = mp[kt * 16 + l16];
#pragma unroll
        for (int r = 0; r < 4; r++) {
            float sv = bf16r(acc[kt][r]) * 0.125f;
            sv = mv ? -INFINITY : sv;
            acc[kt][r] = sv;
            mrow[r] = fmaxf(mrow[r], sv);
        }
    }
#pragma unroll
    for (int off = 1; off < 16; off <<= 1) {
#pragma unroll
        for (int r = 0; r < 4; r++)
            mrow[r] = fmaxf(mrow[r], __shfl_xor(mrow[r], off, 64));
    }
    float srow[4] = {0.f, 0.f, 0.f, 0.f};
#pragma unroll
    for (int kt = 0; kt < 16; kt++) {
#pragma unroll
        for (int r = 0; r < 4; r++) {
            float p = __expf(acc[kt][r] - mrow[r]);
            acc[kt][r] = p;
            srow[r] += p;
        }
    }
#pragma unroll
    for (int off = 1; off < 16; off <<= 1) {
#pragma unroll
        for (int r = 0; r < 4; r++)
            srow[r] += __shfl_xor(srow[r], off, 64);
    }
    float inv[4];
#pragma unroll
    for (int r = 0; r < 4; r++) inv[r] = 1.0f / srow[r];

    ushort* pw = sP + (w * 16) * 264;
#pragma unroll
    for (int kt = 0; kt < 16; kt++) {
#pragma unroll
        for (int r = 0; r < 4; r++) {
            bf16 pv = __float2bfloat16(acc[kt][r] * inv[r]);
            pw[(quad * 4 + r) * 264 + kt * 16 + l16] = *(ushort*)&pv;
        }
    }
    __syncthreads();  // orders P writes (cross-lane) before A-frag reads

    // PV: O[16 q][64 d] per wave = 4 d-tiles; K dim = 256 in 8 chunks of 32
    f32x4 oacc[4];
#pragma unroll
    for (int dt = 0; dt < 4; dt++) oacc[dt] = zero;
    const ushort* vtp = vtbuf + ((size_t)bh * HDD) * NL + quad * 8;
#pragma unroll
    for (int kc = 0; kc < 8; kc++) {
        bf16x8 pa = *(const bf16x8*)(pw + l16 * 264 + kc * 32 + quad * 8);
#pragma unroll
        for (int dt = 0; dt < 4; dt++) {
            bf16x8 vb = *(const bf16x8*)(vtp + (size_t)(dt * 16 + l16) * NL + kc * 32);
            oacc[dt] = __builtin_amdgcn_mfma_f32_16x16x32_bf16(pa, vb, oacc[dt], 0, 0, 0);
        }
    }
    bf16* op = obuf + ((size_t)(b * NS + s0 + w * 16 + quad * 4)) * NE + h * HDD + l16;
#pragma unroll
    for (int dt = 0; dt < 4; dt++) {
#pragma unroll
        for (int r = 0; r < 4; r++)
            op[(size_t)r * NE + dt * 16] = __float2bfloat16(oacc[dt][r]);
    }
}

// ---------------- K5: attn@Wo + bo, AdaLN modulate, +residual, write NCHW
__global__ void __launch_bounds__(256) out_kernel(const bf16* __restrict__ obuf,
                                                  const float* __restrict__ Wo,
                                                  const float* __restrict__ bo,
                                                  const float* __restrict__ mod,
                                                  const float* __restrict__ img_x,
                                                  float* __restrict__ out) {
    int blk = blockIdx.x;
    int b = blk >> 7;
    int s0 = (blk & 127) << 5;
    int t = threadIdx.x;
    __shared__ float ot[NE * 33];
    __shared__ float yt[NC * 17];
    const bf16* op = obuf + ((size_t)b * NS + s0) * NE;
    for (int r = 0; r < 32; r++) {
        ot[t * 33 + r] = __bfloat162float(op[(size_t)r * NE + t]);
    }
    __syncthreads();
    float sh = mod[b * 768 + t];
    float scv = mod[b * 768 + 256 + t];
    float ga = mod[b * 768 + 512 + t];
    float bov = bo[t];
    const float* xg = img_x + ((size_t)b * NC) * NS + s0;
    for (int half = 0; half < 2; half++) {
        float acc[16];
#pragma unroll
        for (int i = 0; i < 16; i++) acc[i] = 0;
        int sb = half * 16;
        for (int e = 0; e < NE; e++) {
            float w = Wo[e * NC + t];
            const float* pp = &ot[e * 33 + sb];
#pragma unroll
            for (int i = 0; i < 16; i++) acc[i] += pp[i] * w;
        }
#pragma unroll
        for (int i = 0; i < 16; i++) {
            float y = ga * ((acc[i] + bov) * (1.f + scv) + sh);
            yt[t * 17 + i] = y;
        }
        __syncthreads();
        int si = t & 15, cg = t >> 4;
        for (int it = 0; it < 16; it++) {
            int c = it * 16 + cg;
            int s = sb + si;
            out[((size_t)b * NC + c) * NS + s0 + s] = yt[c * 17 + si] + xg[(size_t)c * NS + s];
        }
        __syncthreads();
    }
}

extern "C" void kernel_launch(void* const* d_in, const int* in_sizes, int n_in,
                              void* d_out, int out_size, void* d_ws, size_t ws_size,
                              hipStream_t stream) {
    const float* img_x = (const float*)d_in[0];
    const float* refs = (const float*)d_in[1];
    const int* masks = (const int*)d_in[2];
    const float* ref_embeds = (const float*)d_in[3];
    const float* ln_img_w = (const float*)d_in[4];
    const float* ln_img_b = (const float*)d_in[5];
    const float* ln_txt_w = (const float*)d_in[6];
    const float* ln_txt_b = (const float*)d_in[7];
    const float* Wq = (const float*)d_in[8];
    const float* bq = (const float*)d_in[9];
    const float* Wk = (const float*)d_in[10];
    const float* bk = (const float*)d_in[11];
    const float* Wv = (const float*)d_in[12];
    const float* bv = (const float*)d_in[13];
    const float* Wo = (const float*)d_in[14];
    const float* bo = (const float*)d_in[15];
    const float* W_ada = (const float*)d_in[16];
    const float* b_ada = (const float*)d_in[17];
    float* out = (float*)d_out;

    char* ws = (char*)d_ws;
    float* mod = (float*)ws;                                       // 49,152 B
    bf16* kbuf = (bf16*)(ws + 49152);                              // 2 MB
    bf16* vbuf = (bf16*)(ws + 49152 + 2097152);                    // 2 MB
    ushort* vtbuf = (ushort*)(ws + 49152 + 2 * 2097152);           // 2 MB
    bf16* qbuf = (bf16*)(ws + 49152 + 3 * 2097152);                // 33.5 MB
    bf16* obuf = (bf16*)(ws + 49152 + 3 * 2097152 + 33554432);     // 33.5 MB

    hipLaunchKernelGGL(mod_kernel, dim3(NB), dim3(256), 0, stream,
                       ref_embeds, W_ada, b_ada, mod);
    hipLaunchKernelGGL(kv_kernel, dim3(NB * NL), dim3(256), 0, stream,
                       refs, ln_txt_w, ln_txt_b, Wk, bk, Wv, bv, kbuf, vbuf);
    hipLaunchKernelGGL(vt_kernel, dim3(NB * NHH), dim3(256), 0, stream,
                       vbuf, vtbuf);
    hipLaunchKernelGGL(q_kernel, dim3(NB * (NS / 32)), dim3(256), 0, stream,
                       img_x, ln_img_w, ln_img_b, Wq, bq, qbuf);
    hipLaunchKernelGGL(attn_kernel, dim3(NB * NHH * (NS / 64)), dim3(256), 0, stream,
                       qbuf, kbuf, vtbuf, masks, obuf);
    hipLaunchKernelGGL(out_kernel, dim3(NB * (NS / 32)), dim3(256), 0, stream,
                       obuf, Wo, bo, mod, img_x, out);
}

// Round 3
// 486.867 us; speedup vs baseline: 2.2427x; 1.5285x over previous
//
#include <hip/hip_runtime.h>
#include <hip/hip_bf16.h>

#define NB 16
#define NC 256
#define NS 4096
#define NL 256
#define NE 256
#define NHH 4
#define HDD 64

using bf16 = __hip_bfloat16;
typedef short bf16x8 __attribute__((ext_vector_type(8)));
typedef float f32x4 __attribute__((ext_vector_type(4)));

__device__ __forceinline__ float bf16r(float x) {
    return __bfloat162float(__float2bfloat16(x));
}
__device__ __forceinline__ float rsqrt_nr(float x) {
    float r = rsqrtf(x);
    r = r * (1.5f - 0.5f * x * r * r);
    return r;
}
__device__ __forceinline__ float wave_sum(float v) {
#pragma unroll
    for (int o = 32; o > 0; o >>= 1) v += __shfl_down(v, o, 64);
    return v;
}
__device__ __forceinline__ ushort us(float x) {
    bf16 h = __float2bfloat16(x);
    return *(ushort*)&h;
}

// ---------------- K0: transpose weights to bf16 [out][in] so MFMA B/A frags
// (contiguous along k) load straight from global.
__global__ void __launch_bounds__(256) wt_kernel(const float* __restrict__ Wq,
                                                 const float* __restrict__ Wk,
                                                 const float* __restrict__ Wv,
                                                 const float* __restrict__ Wo,
                                                 ushort* __restrict__ wqt,
                                                 ushort* __restrict__ wkt,
                                                 ushort* __restrict__ wvt,
                                                 ushort* __restrict__ wot) {
    int m = blockIdx.x >> 3, strip = blockIdx.x & 7;
    const float* W = (m == 0) ? Wq : (m == 1) ? Wk : (m == 2) ? Wv : Wo;
    ushort* Wt = (m == 0) ? wqt : (m == 1) ? wkt : (m == 2) ? wvt : wot;
    int t = threadIdx.x;
    __shared__ float tile[32 * 257];
    int in0 = strip * 32;
    for (int i = 0; i < 32; i++) tile[i * 257 + t] = W[(size_t)(in0 + i) * 256 + t];
    __syncthreads();
    ushort vals[32];
#pragma unroll
    for (int i = 0; i < 32; i++) vals[i] = us(tile[i * 257 + t]);
#pragma unroll
    for (int i = 0; i < 32; i += 8)
        *(uint4*)(Wt + (size_t)t * 256 + in0 + i) = *(const uint4*)(vals + i);
}

// ---------------- K1: AdaLN modulation: mod = silu(ref_embeds) @ W_ada + b_ada
__global__ void __launch_bounds__(256) mod_kernel(const float* __restrict__ ref_embeds,
                                                  const float* __restrict__ W_ada,
                                                  const float* __restrict__ b_ada,
                                                  float* __restrict__ mod) {
    int b = blockIdx.x, t = threadIdx.x;
    __shared__ float silu[NC];
    float x = ref_embeds[b * NC + t];
    silu[t] = x / (1.f + expf(-x));
    __syncthreads();
    for (int rep = 0; rep < 3; rep++) {
        int j = rep * NC + t;
        float acc = b_ada[j];
        for (int c = 0; c < NC; c++) acc += silu[c] * W_ada[c * 3 * NC + j];
        mod[b * 3 * NC + j] = acc;
    }
}

// ---------------- K2: LN(refs) -> K,V projections via MFMA. Block = 64 text rows.
__global__ void __launch_bounds__(256) kv_kernel(const float* __restrict__ refs,
                                                 const float* __restrict__ lw,
                                                 const float* __restrict__ lb,
                                                 const ushort* __restrict__ Wkt,
                                                 const float* __restrict__ bk,
                                                 const ushort* __restrict__ Wvt,
                                                 const float* __restrict__ bv,
                                                 bf16* __restrict__ kbuf,
                                                 bf16* __restrict__ vbuf) {
    int blk = blockIdx.x;  // b*4 + lgroup
    int b = blk >> 2;
    int l0 = (blk & 3) << 6;
    int t = threadIdx.x;
    __shared__ ushort At[64 * 264];
    __shared__ float lws[NC], lbs[NC];
    lws[t] = lw[t];
    lbs[t] = lb[t];
    int r = t >> 2, j = t & 3;
    const float* rp = refs + ((size_t)(b * NL + l0 + r)) * NC + j * 64;
    float v[64];
#pragma unroll
    for (int i = 0; i < 16; i++) {
        float4 f = *(const float4*)(rp + i * 4);
        v[i * 4 + 0] = f.x; v[i * 4 + 1] = f.y; v[i * 4 + 2] = f.z; v[i * 4 + 3] = f.w;
    }
    float s = 0;
#pragma unroll
    for (int i = 0; i < 64; i++) s += v[i];
    s += __shfl_xor(s, 1, 64);
    s += __shfl_xor(s, 2, 64);
    float mu = s * (1.f / NC);
    float vr = 0;
#pragma unroll
    for (int i = 0; i < 64; i++) {
        float d = v[i] - mu;
        vr += d * d;
    }
    vr += __shfl_xor(vr, 1, 64);
    vr += __shfl_xor(vr, 2, 64);
    float rs = rsqrt_nr(vr * (1.f / NC) + 1e-5f);
    __syncthreads();  // lws/lbs ready
    ushort nv[64];
#pragma unroll
    for (int i = 0; i < 64; i++) {
        int c = j * 64 + i;
        nv[i] = us((v[i] - mu) * rs * lws[c] + lbs[c]);
    }
#pragma unroll
    for (int i = 0; i < 64; i += 4)
        *(uint2*)(At + r * 264 + j * 64 + i) = *(const uint2*)(nv + i);
    __syncthreads();

    int w = t >> 6, lane = t & 63, l16 = lane & 15, quad = lane >> 4;
    int r0 = w * 16;
    f32x4 zero = {0.f, 0.f, 0.f, 0.f};
    f32x4 ak[16], av[16];
#pragma unroll
    for (int et = 0; et < 16; et++) { ak[et] = zero; av[et] = zero; }
    const ushort* ap = At + (r0 + l16) * 264 + quad * 8;
    const ushort* kp = Wkt + (size_t)l16 * NC + quad * 8;
    const ushort* vp = Wvt + (size_t)l16 * NC + quad * 8;
#pragma unroll
    for (int kc = 0; kc < 8; kc++) {
        bf16x8 a = *(const bf16x8*)(ap + kc * 32);
#pragma unroll
        for (int et = 0; et < 16; et++) {
            bf16x8 bbk = *(const bf16x8*)(kp + (size_t)et * 16 * NC + kc * 32);
            ak[et] = __builtin_amdgcn_mfma_f32_16x16x32_bf16(a, bbk, ak[et], 0, 0, 0);
        }
#pragma unroll
        for (int et = 0; et < 16; et++) {
            bf16x8 bbv = *(const bf16x8*)(vp + (size_t)et * 16 * NC + kc * 32);
            av[et] = __builtin_amdgcn_mfma_f32_16x16x32_bf16(a, bbv, av[et], 0, 0, 0);
        }
    }
#pragma unroll
    for (int et = 0; et < 16; et++) {
        int e = et * 16 + l16;
        float bkv = bk[e], bvv = bv[e];
#pragma unroll
        for (int rr = 0; rr < 4; rr++) {
            size_t row = (size_t)(b * NL + l0 + r0 + quad * 4 + rr);
            kbuf[row * NE + e] = __float2bfloat16(ak[et][rr] + bkv);
            vbuf[row * NE + e] = __float2bfloat16(av[et][rr] + bvv);
        }
    }
}

// ---------------- K2b: transpose V per head: vbuf [B,L,E] -> vtbuf [B,H,HD,L]
__global__ void __launch_bounds__(256) vt_kernel(const bf16* __restrict__ vbuf,
                                                 ushort* __restrict__ vtbuf) {
    int bh = blockIdx.x;
    int b = bh >> 2, h = bh & 3;
    int t = threadIdx.x;
    __shared__ ushort tile[64 * 264];
    const ushort* vp = (const ushort*)vbuf + ((size_t)b * NL) * NE + h * HDD;
#pragma unroll
    for (int i = 0; i < 8; i++) {
        int l = i * 32 + (t >> 3);
        uint4 v = *(const uint4*)(vp + (size_t)l * NE + (t & 7) * 8);
        const ushort* v8 = (const ushort*)&v;
#pragma unroll
        for (int j = 0; j < 8; j++) tile[((t & 7) * 8 + j) * 264 + l] = v8[j];
    }
    __syncthreads();
    ushort* op = vtbuf + (size_t)bh * HDD * NL;
#pragma unroll
    for (int i = 0; i < 8; i++) {
        int d = i * 8 + (t >> 5);
        int l = (t & 31) * 8;
        *(uint4*)(op + (size_t)d * NL + l) = *(const uint4*)(tile + d * 264 + l);
    }
}

// ---------------- K3: LN(img tokens) -> Q projection via MFMA (bf16 [B,S,E])
__global__ void __launch_bounds__(256) q_kernel(const float* __restrict__ img_x,
                                                const float* __restrict__ lw,
                                                const float* __restrict__ lb,
                                                const ushort* __restrict__ Wqt,
                                                const float* __restrict__ bq,
                                                bf16* __restrict__ qbuf) {
    int blk = blockIdx.x;
    int b = blk >> 7;
    int s0 = (blk & 127) << 5;
    int t = threadIdx.x;
    int sl = t & 31, ch = t >> 5;
    __shared__ float tile[NC * 33];
    __shared__ ushort At[32 * 264];
    __shared__ float part[256];
    __shared__ float mu_s[32], rs_s[32];
    const float* xp = img_x + ((size_t)b * NC) * NS + s0;
    for (int c0 = 0; c0 < 32; c0++) {
        int c = c0 * 8 + ch;
        tile[c * 33 + sl] = xp[(size_t)c * NS + sl];
    }
    __syncthreads();
    float ps = 0;
    for (int c = ch * 32; c < ch * 32 + 32; c++) ps += tile[c * 33 + sl];
    part[t] = ps;
    __syncthreads();
    if (t < 32) {
        float m = 0;
        for (int j = 0; j < 8; j++) m += part[j * 32 + t];
        mu_s[t] = m * (1.f / NC);
    }
    __syncthreads();
    float mu = mu_s[sl];
    ps = 0;
    for (int c = ch * 32; c < ch * 32 + 32; c++) {
        float d = tile[c * 33 + sl] - mu;
        ps += d * d;
    }
    part[t] = ps;
    __syncthreads();
    if (t < 32) {
        float vv = 0;
        for (int j = 0; j < 8; j++) vv += part[j * 32 + t];
        rs_s[t] = rsqrt_nr(vv * (1.f / NC) + 1e-5f);
    }
    __syncthreads();
    float rs = rs_s[sl];
    for (int c = ch * 32; c < ch * 32 + 32; c++) {
        At[sl * 264 + c] = us((tile[c * 33 + sl] - mu) * rs * lw[c] + lb[c]);
    }
    __syncthreads();

    int w = t >> 6, lane = t & 63, l16 = lane & 15, quad = lane >> 4;
    int r0 = (w & 1) * 16, e0 = (w >> 1) * 128;
    f32x4 zero = {0.f, 0.f, 0.f, 0.f};
    f32x4 acc[8];
#pragma unroll
    for (int dt = 0; dt < 8; dt++) acc[dt] = zero;
    const ushort* ap = At + (r0 + l16) * 264 + quad * 8;
    const ushort* bp = Wqt + (size_t)(e0 + l16) * NC + quad * 8;
#pragma unroll
    for (int kc = 0; kc < 8; kc++) {
        bf16x8 a = *(const bf16x8*)(ap + kc * 32);
#pragma unroll
        for (int dt = 0; dt < 8; dt++) {
            bf16x8 bb = *(const bf16x8*)(bp + (size_t)dt * 16 * NC + kc * 32);
            acc[dt] = __builtin_amdgcn_mfma_f32_16x16x32_bf16(a, bb, acc[dt], 0, 0, 0);
        }
    }
#pragma unroll
    for (int dt = 0; dt < 8; dt++) {
        int e = e0 + dt * 16 + l16;
        float bqv = bq[e];
#pragma unroll
        for (int r = 0; r < 4; r++) {
            int s = s0 + r0 + quad * 4 + r;
            qbuf[((size_t)b * NS + s) * NE + e] = __float2bfloat16(acc[dt][r] + bqv);
        }
    }
}

// ---------------- K4: MFMA attention (unchanged from round 2)
__global__ void __launch_bounds__(256) attn_kernel(const bf16* __restrict__ qbuf,
                                                   const bf16* __restrict__ kbuf,
                                                   const ushort* __restrict__ vtbuf,
                                                   const int* __restrict__ masks,
                                                   bf16* __restrict__ obuf) {
    int blk = blockIdx.x;
    int st = blk & 63;
    int bh = blk >> 6;
    int h = bh & 3;
    int b = bh >> 2;
    int s0 = st << 6;
    int t = threadIdx.x;
    int w = t >> 6, lane = t & 63;
    int l16 = lane & 15, quad = lane >> 4;

    __shared__ ushort sP[64 * 264];

    const ushort* qp = (const ushort*)qbuf +
                       ((size_t)(b * NS + s0 + w * 16 + l16)) * NE + h * HDD + quad * 8;
    bf16x8 af0 = *(const bf16x8*)qp;
    bf16x8 af1 = *(const bf16x8*)(qp + 32);

    f32x4 zero = {0.f, 0.f, 0.f, 0.f};
    f32x4 acc[16];
#pragma unroll
    for (int kt = 0; kt < 16; kt++) acc[kt] = zero;

    const ushort* kp0 = (const ushort*)kbuf + ((size_t)(b * NL)) * NE + h * HDD + quad * 8;
#pragma unroll
    for (int kt = 0; kt < 16; kt++) {
        const ushort* kp = kp0 + (size_t)(kt * 16 + l16) * NE;
        bf16x8 bf0 = *(const bf16x8*)kp;
        bf16x8 bf1 = *(const bf16x8*)(kp + 32);
        acc[kt] = __builtin_amdgcn_mfma_f32_16x16x32_bf16(af0, bf0, acc[kt], 0, 0, 0);
        acc[kt] = __builtin_amdgcn_mfma_f32_16x16x32_bf16(af1, bf1, acc[kt], 0, 0, 0);
    }

    const int* mp = masks + b * NL;
    float mrow[4] = {-INFINITY, -INFINITY, -INFINITY, -INFINITY};
#pragma unroll
    for (int kt = 0; kt < 16; kt++) {
        int mv = mp[kt * 16 + l16];
#pragma unroll
        for (int r = 0; r < 4; r++) {
            float sv = bf16r(acc[kt][r]) * 0.125f;
            sv = mv ? -INFINITY : sv;
            acc[kt][r] = sv;
            mrow[r] = fmaxf(mrow[r], sv);
        }
    }
#pragma unroll
    for (int off = 1; off < 16; off <<= 1) {
#pragma unroll
        for (int r = 0; r < 4; r++)
            mrow[r] = fmaxf(mrow[r], __shfl_xor(mrow[r], off, 64));
    }
    float srow[4] = {0.f, 0.f, 0.f, 0.f};
#pragma unroll
    for (int kt = 0; kt < 16; kt++) {
#pragma unroll
        for (int r = 0; r < 4; r++) {
            float p = __expf(acc[kt][r] - mrow[r]);
            acc[kt][r] = p;
            srow[r] += p;
        }
    }
#pragma unroll
    for (int off = 1; off < 16; off <<= 1) {
#pragma unroll
        for (int r = 0; r < 4; r++)
            srow[r] += __shfl_xor(srow[r], off, 64);
    }
    float inv[4];
#pragma unroll
    for (int r = 0; r < 4; r++) inv[r] = 1.0f / srow[r];

    ushort* pw = sP + (w * 16) * 264;
#pragma unroll
    for (int kt = 0; kt < 16; kt++) {
#pragma unroll
        for (int r = 0; r < 4; r++) {
            pw[(quad * 4 + r) * 264 + kt * 16 + l16] = us(acc[kt][r] * inv[r]);
        }
    }
    __syncthreads();

    f32x4 oacc[4];
#pragma unroll
    for (int dt = 0; dt < 4; dt++) oacc[dt] = zero;
    const ushort* vtp = vtbuf + ((size_t)bh * HDD) * NL + quad * 8;
#pragma unroll
    for (int kc = 0; kc < 8; kc++) {
        bf16x8 pa = *(const bf16x8*)(pw + l16 * 264 + kc * 32 + quad * 8);
#pragma unroll
        for (int dt = 0; dt < 4; dt++) {
            bf16x8 vb = *(const bf16x8*)(vtp + (size_t)(dt * 16 + l16) * NL + kc * 32);
            oacc[dt] = __builtin_amdgcn_mfma_f32_16x16x32_bf16(pa, vb, oacc[dt], 0, 0, 0);
        }
    }
    bf16* op = obuf + ((size_t)(b * NS + s0 + w * 16 + quad * 4)) * NE + h * HDD + l16;
#pragma unroll
    for (int dt = 0; dt < 4; dt++) {
#pragma unroll
        for (int r = 0; r < 4; r++)
            op[(size_t)r * NE + dt * 16] = __float2bfloat16(oacc[dt][r]);
    }
}

// ---------------- K5: Y^T = Wo^T . o^T via MFMA -> AdaLN -> +x -> out [B,C,S].
// A-frags from Wot (global), B-frags from obuf (global), D lands [c][s]: no LDS.
__global__ void __launch_bounds__(256) out_kernel(const bf16* __restrict__ obuf,
                                                  const ushort* __restrict__ Wot,
                                                  const float* __restrict__ bo,
                                                  const float* __restrict__ mod,
                                                  const float* __restrict__ img_x,
                                                  float* __restrict__ out) {
    int blk = blockIdx.x;  // b * 64 + s-tile
    int b = blk >> 6;
    int s0 = (blk & 63) << 6;
    int t = threadIdx.x;
    int w = t >> 6, lane = t & 63, l16 = lane & 15, quad = lane >> 4;
    int c0 = w * 64;

    f32x4 zero = {0.f, 0.f, 0.f, 0.f};
    f32x4 acc[4][4];
#pragma unroll
    for (int ct = 0; ct < 4; ct++)
#pragma unroll
        for (int st = 0; st < 4; st++) acc[ct][st] = zero;

    const ushort* ap0 = Wot + (size_t)(c0 + l16) * NE + quad * 8;
    const ushort* bp0 = (const ushort*)obuf + ((size_t)(b * NS + s0 + l16)) * NE + quad * 8;
#pragma unroll
    for (int kc = 0; kc < 8; kc++) {
        bf16x8 a[4], bb[4];
#pragma unroll
        for (int ct = 0; ct < 4; ct++)
            a[ct] = *(const bf16x8*)(ap0 + (size_t)ct * 16 * NE + kc * 32);
#pragma unroll
        for (int st = 0; st < 4; st++)
            bb[st] = *(const bf16x8*)(bp0 + (size_t)st * 16 * NE + kc * 32);
#pragma unroll
        for (int ct = 0; ct < 4; ct++)
#pragma unroll
            for (int st = 0; st < 4; st++)
                acc[ct][st] = __builtin_amdgcn_mfma_f32_16x16x32_bf16(a[ct], bb[st], acc[ct][st], 0, 0, 0);
    }

#pragma unroll
    for (int ct = 0; ct < 4; ct++) {
#pragma unroll
        for (int r = 0; r < 4; r++) {
            int c = c0 + ct * 16 + quad * 4 + r;
            float sh = mod[b * 768 + c];
            float scv = mod[b * 768 + 256 + c];
            float ga = mod[b * 768 + 512 + c];
            float bov = bo[c];
            const float* xr = img_x + ((size_t)(b * NC + c)) * NS + s0;
            float* orow = out + ((size_t)(b * NC + c)) * NS + s0;
#pragma unroll
            for (int st = 0; st < 4; st++) {
                float y = ga * ((acc[ct][st][r] + bov) * (1.f + scv) + sh) + xr[st * 16 + l16];
                orow[st * 16 + l16] = y;
            }
        }
    }
}

extern "C" void kernel_launch(void* const* d_in, const int* in_sizes, int n_in,
                              void* d_out, int out_size, void* d_ws, size_t ws_size,
                              hipStream_t stream) {
    const float* img_x = (const float*)d_in[0];
    const float* refs = (const float*)d_in[1];
    const int* masks = (const int*)d_in[2];
    const float* ref_embeds = (const float*)d_in[3];
    const float* ln_img_w = (const float*)d_in[4];
    const float* ln_img_b = (const float*)d_in[5];
    const float* ln_txt_w = (const float*)d_in[6];
    const float* ln_txt_b = (const float*)d_in[7];
    const float* Wq = (const float*)d_in[8];
    const float* bq = (const float*)d_in[9];
    const float* Wk = (const float*)d_in[10];
    const float* bk = (const float*)d_in[11];
    const float* Wv = (const float*)d_in[12];
    const float* bv = (const float*)d_in[13];
    const float* Wo = (const float*)d_in[14];
    const float* bo = (const float*)d_in[15];
    const float* W_ada = (const float*)d_in[16];
    const float* b_ada = (const float*)d_in[17];
    float* out = (float*)d_out;

    char* ws = (char*)d_ws;
    float* mod = (float*)ws;                               // 49152 B
    ushort* wqt = (ushort*)(ws + 49152);                   // 128 KB
    ushort* wkt = (ushort*)(ws + 180224);                  // 128 KB
    ushort* wvt = (ushort*)(ws + 311296);                  // 128 KB
    ushort* wot = (ushort*)(ws + 442368);                  // 128 KB
    bf16* kbuf = (bf16*)(ws + 573440);                     // 2 MB
    ushort* vtbuf = (ushort*)(ws + 2670592);               // 2 MB
    bf16* qbuf = (bf16*)(ws + 4767744);                    // 33.5 MB
    bf16* obuf = (bf16*)(ws + 38322176);                   // 33.5 MB
    bf16* vbuf = obuf;  // alias: dead after vt_kernel, before attn writes obuf

    hipLaunchKernelGGL(wt_kernel, dim3(32), dim3(256), 0, stream,
                       Wq, Wk, Wv, Wo, wqt, wkt, wvt, wot);
    hipLaunchKernelGGL(mod_kernel, dim3(NB), dim3(256), 0, stream,
                       ref_embeds, W_ada, b_ada, mod);
    hipLaunchKernelGGL(kv_kernel, dim3(NB * 4), dim3(256), 0, stream,
                       refs, ln_txt_w, ln_txt_b, wkt, bk, wvt, bv, kbuf, vbuf);
    hipLaunchKernelGGL(vt_kernel, dim3(NB * NHH), dim3(256), 0, stream,
                       vbuf, vtbuf);
    hipLaunchKernelGGL(q_kernel, dim3(NB * (NS / 32)), dim3(256), 0, stream,
                       img_x, ln_img_w, ln_img_b, wqt, bq, qbuf);
    hipLaunchKernelGGL(attn_kernel, dim3(NB * NHH * (NS / 64)), dim3(256), 0, stream,
                       qbuf, kbuf, vtbuf, masks, obuf);
    hipLaunchKernelGGL(out_kernel, dim3(NB * (NS / 64)), dim3(256), 0, stream,
                       obuf, wot, bo, mod, img_x, out);
}